// Round 16
// baseline (128.652 us; speedup 1.0000x reference)
//
#include <hip/hip_runtime.h>
#include <hip/hip_bf16.h>
#include <stdint.h>

#define NROWS 4096
#define DIMS  2048
#define BM    256
#define BKB   64              // K-slot = 64 int8 bytes
#define NTILES (DIMS / BKB)   // 32
#define NTB   (NROWS / BM)    // 16 -> 256 blocks
#define MARGIN_F 0.3f

typedef __attribute__((ext_vector_type(4))) int   i32x4;
typedef __attribute__((ext_vector_type(4))) float f32x4;

__device__ inline void atomicMaxF(float* addr, float v) {
  if (v >= 0.f) atomicMax((int*)addr, __float_as_int(v));
  else          atomicMin((unsigned int*)addr, __float_as_uint(v));
}
__device__ inline void atomicMinF(float* addr, float v) {
  if (v >= 0.f) atomicMin((int*)addr, __float_as_int(v));
  else          atomicMax((unsigned int*)addr, __float_as_uint(v));
}

// ------- normalize + per-row int8 quantization (q = rint(x*127/amax)) -------
__global__ __launch_bounds__(256) void norm_kernel(const float* __restrict__ in,
                                                   char* __restrict__ l2q,
                                                   float* __restrict__ recip,
                                                   float* __restrict__ dap,
                                                   float* __restrict__ dan) {
  int row = blockIdx.x;
  int t = threadIdx.x;
  const float4* rin = (const float4*)(in + (size_t)row * DIMS);
  float4 v0 = rin[t];
  float4 v1 = rin[t + 256];
  float ss = v0.x*v0.x + v0.y*v0.y + v0.z*v0.z + v0.w*v0.w
           + v1.x*v1.x + v1.y*v1.y + v1.z*v1.z + v1.w*v1.w;
  float am = fmaxf(fmaxf(fmaxf(fabsf(v0.x), fabsf(v0.y)), fmaxf(fabsf(v0.z), fabsf(v0.w))),
                   fmaxf(fmaxf(fabsf(v1.x), fabsf(v1.y)), fmaxf(fabsf(v1.z), fabsf(v1.w))));
  #pragma unroll
  for (int s = 1; s < 64; s <<= 1) {
    ss += __shfl_xor(ss, s);
    am = fmaxf(am, __shfl_xor(am, s));
  }
  __shared__ float wsum[4], wmax[4];
  if ((t & 63) == 0) { wsum[t >> 6] = ss; wmax[t >> 6] = am; }
  __syncthreads();
  float tot = wsum[0] + wsum[1] + wsum[2] + wsum[3];
  float amax = fmaxf(fmaxf(wmax[0], wmax[1]), fmaxf(wmax[2], wmax[3]));
  float rn = 1.0f / sqrtf(tot);
  float qs = 127.0f / amax;
  int q0 = (int)rintf(v0.x * qs), q1 = (int)rintf(v0.y * qs);
  int q2 = (int)rintf(v0.z * qs), q3 = (int)rintf(v0.w * qs);
  int q4 = (int)rintf(v1.x * qs), q5 = (int)rintf(v1.y * qs);
  int q6 = (int)rintf(v1.z * qs), q7 = (int)rintf(v1.w * qs);
  int p0 = (q0 & 255) | ((q1 & 255) << 8) | ((q2 & 255) << 16) | (q3 << 24);
  int p1 = (q4 & 255) | ((q5 & 255) << 8) | ((q6 & 255) << 16) | (q7 << 24);
  int* orow = (int*)(l2q + (size_t)row * DIMS);
  orow[t] = p0;
  orow[t + 256] = p1;
  if (t == 0) {
    recip[row] = amax * rn / 127.0f;
    dap[row] = -__builtin_inff();
    dan[row] = __builtin_inff();
  }
}

// ---------------- fused int8 GEMM (acc = Q . Q^T) + masked row max/min ----------------
// LDS-FREE: the 8 MB int8 input is L2/L3-resident, so MFMA fragments are
// loaded DIRECTLY from global into a 2-slot register ring. Per wave per
// 64-K slot: 8 A-frag + 4 B-frag global_load_dwordx4 (lane (laneq,g) reads
// row-base + kt*64 + g*16 -- the 4 k-slot quarters coalesce onto the same
// 64B lines; operands bit-identical to r12's verified LDS path). No LDS,
// no barriers, no staging in the K-loop: per-wave counted vmcnt(12) waits
// (FIFO drain, m135) with prefetch distance = 1 full slot (~2000 cy >> L2
// latency). This deletes the ~2000 cy/slot CONST (barrier skew + publish
// gates + lgkm drains) that every LDS-staged variant (r4-r15) paid.
// 256x256 tile, 8 waves (2M x 4N, wave tile 128x64), mfma_i32_16x16x64_i8.
__global__ __launch_bounds__(512, 2) void gemm_reduce_kernel(
    const char* __restrict__ l2q, const int* __restrict__ tgt,
    const float* __restrict__ recip,
    float* __restrict__ dap, float* __restrict__ dan) {
  // XCD-chunked bijective swizzle (256 blocks, 8 XCDs -> 32 contiguous per XCD)
  int c = blockIdx.x;
  int swz = (c & 7) * 32 + (c >> 3);
  int bi = swz >> 4, bj = swz & 15;

  int tid = threadIdx.x;
  int lane = tid & 63, w = tid >> 6;
  int wr = w >> 2;        // 0..1  (M half: 128 rows)
  int nc = w & 3;         // 0..3  (N quarter: 64 cols)
  int laneq = lane & 15, g = lane >> 4;

  i32x4 acc[8][4];
  #pragma unroll
  for (int m = 0; m < 8; m++)
    #pragma unroll
    for (int n = 0; n < 4; n++) acc[m][n] = (i32x4){0, 0, 0, 0};

  // per-lane fragment byte offsets (uint32; matrix is 8 MB)
  uint32_t offA = (uint32_t)(bi * BM + wr * 128 + laneq) * DIMS + g * 16;
  uint32_t offB = (uint32_t)(bj * BM + nc * 64 + laneq) * DIMS + g * 16;

  i32x4 aX[8], bX[4], aY[8], bY[4];

  #define LOADA(DST, OFF)                                                     \
    _Pragma("unroll")                                                         \
    for (int m = 0; m < 8; m++)                                               \
      DST[m] = *(const i32x4*)(l2q + (OFF) + m * (16 * DIMS));
  #define LOADB(DST, OFF)                                                     \
    _Pragma("unroll")                                                         \
    for (int n = 0; n < 4; n++)                                               \
      DST[n] = *(const i32x4*)(l2q + (OFF) + n * (16 * DIMS));

  #define MFMA32(AR, BR)                                                      \
    __builtin_amdgcn_s_setprio(1);                                            \
    _Pragma("unroll")                                                         \
    for (int m = 0; m < 8; m++)                                               \
      _Pragma("unroll")                                                       \
      for (int n = 0; n < 4; n++)                                             \
        acc[m][n] = __builtin_amdgcn_mfma_i32_16x16x64_i8(                    \
            AR[m], BR[n], acc[m][n], 0, 0, 0);                                \
    __builtin_amdgcn_s_setprio(0);

  #define SB __builtin_amdgcn_sched_barrier(0);
  #define VMW(N) asm volatile("s_waitcnt vmcnt(" #N ")" ::: "memory"); SB

  // prologue: issue slots 0 and 1 (24 loads in flight)
  LOADA(aX, offA) LOADB(bX, offB) offA += BKB; offB += BKB;
  LOADA(aY, offA) LOADB(bY, offB) offA += BKB; offB += BKB;

  // steady state: compute slot kt, issue slot kt+2 into the freed buffer.
  // vmcnt(12) drains exactly the oldest 12 (slot kt's loads).
  #pragma unroll 1
  for (int kt = 0; kt < NTILES - 2; kt += 2) {
    VMW(12)
    MFMA32(aX, bX)
    LOADA(aX, offA) LOADB(bX, offB) offA += BKB; offB += BKB;
    VMW(12)
    MFMA32(aY, bY)
    LOADA(aY, offA) LOADB(bY, offB) offA += BKB; offB += BKB;
  }
  // tail: slots 30, 31
  VMW(12)
  MFMA32(aX, bX)
  VMW(0)
  MFMA32(aY, bY)

  // ---- fused masked reduction (r12-identical, verified) ----
  // acc[m][n][r] = Gq[bi*256 + wr*128 + m*16 + g*4 + r]
  //                  [bj*256 + nc*64  + n*16 + laneq]
  int tcol[4];
  float tcr[4];
  #pragma unroll
  for (int n = 0; n < 4; n++) {
    int idx = bj * BM + nc * 64 + n * 16 + laneq;
    tcol[n] = tgt[idx];
    tcr[n] = recip[idx];
  }
  int rbase = bi * BM + wr * 128 + g * 4;

  #pragma unroll
  for (int m = 0; m < 8; m++) {
    #pragma unroll
    for (int r = 0; r < 4; r++) {
      int grow = rbase + m * 16 + r;
      int trow = tgt[grow];
      float rrw = recip[grow];
      float ap = -__builtin_inff(), an = __builtin_inff();
      #pragma unroll
      for (int n = 0; n < 4; n++) {
        float d = -(float)acc[m][n][r] * rrw * tcr[n];
        bool same = (trow == tcol[n]);
        ap = same ? fmaxf(ap, d) : ap;
        an = same ? an : fminf(an, d);
      }
      #pragma unroll
      for (int s = 1; s < 16; s <<= 1) {
        ap = fmaxf(ap, __shfl_xor(ap, s));
        an = fminf(an, __shfl_xor(an, s));
      }
      if (laneq == 0) {
        atomicMaxF(&dap[grow], ap);
        atomicMinF(&dan[grow], an);
      }
    }
  }
  #undef LOADA
  #undef LOADB
  #undef MFMA32
  #undef SB
  #undef VMW
}

// ---------------- final loss ----------------
__global__ __launch_bounds__(256) void loss_kernel(const float* __restrict__ dap,
                                                   const float* __restrict__ dan,
                                                   float* __restrict__ out) {
  int t = threadIdx.x;
  float s = 0.f;
  for (int i = t; i < NROWS; i += 256) {
    float v = dap[i] - dan[i] + MARGIN_F;
    s += v > 0.f ? v : 0.f;
  }
  #pragma unroll
  for (int sh = 1; sh < 64; sh <<= 1) s += __shfl_xor(s, sh);
  __shared__ float ws[4];
  if ((t & 63) == 0) ws[t >> 6] = s;
  __syncthreads();
  if (t == 0) out[0] = (ws[0] + ws[1] + ws[2] + ws[3]) * (1.0f / (float)NROWS);
}

extern "C" void kernel_launch(void* const* d_in, const int* in_sizes, int n_in,
                              void* d_out, int out_size, void* d_ws, size_t ws_size,
                              hipStream_t stream) {
  const float* inputs = (const float*)d_in[0];
  const int* targets = (const int*)d_in[1];
  char* l2q = (char*)d_ws;
  float* recip = (float*)((char*)d_ws + (size_t)NROWS * DIMS);
  float* dap = recip + NROWS;
  float* dan = dap + NROWS;
  float* out = (float*)d_out;

  hipLaunchKernelGGL(norm_kernel, dim3(NROWS), dim3(256), 0, stream,
                     inputs, l2q, recip, dap, dan);
  hipLaunchKernelGGL(gemm_reduce_kernel, dim3(NTB * NTB), dim3(512), 0, stream,
                     l2q, targets, recip, dap, dan);
  hipLaunchKernelGGL(loss_kernel, dim3(1), dim3(256), 0, stream, dap, dan, out);
}

// Round 17
// 65.601 us; speedup vs baseline: 1.9611x; 1.9611x over previous
//
#include <hip/hip_runtime.h>
#include <hip/hip_bf16.h>
#include <stdint.h>

#define NROWS 4096
#define DIMS  2048
#define BM    128             // tile 128x128
#define BKB   64              // K-tile = 64 int8 = 64 B rows
#define NTILES (DIMS / BKB)   // 32
#define NTB   (NROWS / BM)    // 32 -> 1024 blocks
#define MARGIN_F 0.3f

typedef __attribute__((ext_vector_type(4))) int   i32x4;
typedef __attribute__((ext_vector_type(4))) float f32x4;

__device__ inline void atomicMaxF(float* addr, float v) {
  if (v >= 0.f) atomicMax((int*)addr, __float_as_int(v));
  else          atomicMin((unsigned int*)addr, __float_as_uint(v));
}
__device__ inline void atomicMinF(float* addr, float v) {
  if (v >= 0.f) atomicMin((int*)addr, __float_as_int(v));
  else          atomicMax((unsigned int*)addr, __float_as_uint(v));
}

__device__ inline void load_lds16(const void* g, void* l) {
  __builtin_amdgcn_global_load_lds(
      (const __attribute__((address_space(1))) void*)(g),
      (__attribute__((address_space(3))) void*)(l), 16, 0, 0);
}

// ------- normalize + per-row int8 quantization (q = rint(x*127/amax)) -------
__global__ __launch_bounds__(256) void norm_kernel(const float* __restrict__ in,
                                                   char* __restrict__ l2q,
                                                   float* __restrict__ recip,
                                                   float* __restrict__ dap,
                                                   float* __restrict__ dan) {
  int row = blockIdx.x;
  int t = threadIdx.x;
  const float4* rin = (const float4*)(in + (size_t)row * DIMS);
  float4 v0 = rin[t];
  float4 v1 = rin[t + 256];
  float ss = v0.x*v0.x + v0.y*v0.y + v0.z*v0.z + v0.w*v0.w
           + v1.x*v1.x + v1.y*v1.y + v1.z*v1.z + v1.w*v1.w;
  float am = fmaxf(fmaxf(fmaxf(fabsf(v0.x), fabsf(v0.y)), fmaxf(fabsf(v0.z), fabsf(v0.w))),
                   fmaxf(fmaxf(fabsf(v1.x), fabsf(v1.y)), fmaxf(fabsf(v1.z), fabsf(v1.w))));
  #pragma unroll
  for (int s = 1; s < 64; s <<= 1) {
    ss += __shfl_xor(ss, s);
    am = fmaxf(am, __shfl_xor(am, s));
  }
  __shared__ float wsum[4], wmax[4];
  if ((t & 63) == 0) { wsum[t >> 6] = ss; wmax[t >> 6] = am; }
  __syncthreads();
  float tot = wsum[0] + wsum[1] + wsum[2] + wsum[3];
  float amax = fmaxf(fmaxf(wmax[0], wmax[1]), fmaxf(wmax[2], wmax[3]));
  float rn = 1.0f / sqrtf(tot);
  float qs = 127.0f / amax;
  int q0 = (int)rintf(v0.x * qs), q1 = (int)rintf(v0.y * qs);
  int q2 = (int)rintf(v0.z * qs), q3 = (int)rintf(v0.w * qs);
  int q4 = (int)rintf(v1.x * qs), q5 = (int)rintf(v1.y * qs);
  int q6 = (int)rintf(v1.z * qs), q7 = (int)rintf(v1.w * qs);
  int p0 = (q0 & 255) | ((q1 & 255) << 8) | ((q2 & 255) << 16) | (q3 << 24);
  int p1 = (q4 & 255) | ((q5 & 255) << 8) | ((q6 & 255) << 16) | (q7 << 24);
  int* orow = (int*)(l2q + (size_t)row * DIMS);
  orow[t] = p0;
  orow[t + 256] = p1;
  if (t == 0) {
    recip[row] = amax * rn / 127.0f;
    dap[row] = -__builtin_inff();
    dan[row] = __builtin_inff();
  }
}

// ---------------- fused int8 GEMM (acc = Q . Q^T) + masked row max/min ----------------
// m97-SKELETON at 4 blocks/CU (the one HW-validated simple structure):
// 128x128 tile, 4 waves (2x2, wave tile 64x64), BK=64 int8,
// mfma_i32_16x16x64_i8 (16 MFMA/wave/K-tile), 16 KB SINGLE-BUFFER LDS,
// plain 2-syncthreads loop: {sync; stage tile (4 gload_lds); sync (drains
// vmcnt); 8 ds_read_b128 + 16 MFMA compiler-scheduled}.
// __launch_bounds__(256,4) + 16 KB LDS -> 4 independent blocks/CU
// (16 waves/CU): cross-block overlap hides the per-tile drain/barrier cost
// (m114/m97 mechanism) that barrier-lockstepped 1-2-block r4-r15 exposed.
// Addressing verified r4-r15: staging linear LDS dest + pre-swizzled
// coalesced global source; read swizzle fc = (g^((laneq>>1)&3))*16; 0 bank
// conflicts; epilogue geometry = r1 (verified) with r9 recip scaling.
__global__ __launch_bounds__(256, 4) void gemm_reduce_kernel(
    const char* __restrict__ l2q, const int* __restrict__ tgt,
    const float* __restrict__ recip,
    float* __restrict__ dap, float* __restrict__ dan) {
  __shared__ __attribute__((aligned(16))) char ldsbuf[16384];  // A 8K + B 8K

  // XCD-chunked bijective swizzle (1024 blocks, 8 XCDs -> 128 contiguous per XCD)
  int c = blockIdx.x;
  int swz = (c & 7) * 128 + (c >> 3);
  int bi = swz >> 5, bj = swz & 31;

  int tid = threadIdx.x;
  int lane = tid & 63, w = tid >> 6;
  int wr = w >> 1;        // 0..1  (M half: 64 rows)
  int nc = w & 1;         // 0..1  (N half: 64 cols)
  int laneq = lane & 15, g = lane >> 4;

  i32x4 acc[4][4];
  #pragma unroll
  for (int m = 0; m < 4; m++)
    #pragma unroll
    for (int n = 0; n < 4; n++) acc[m][n] = (i32x4){0, 0, 0, 0};

  // --- staging source: slot s = tid covers row tid>>2 (gload0) / +64
  //     (gload1); data chunk q = (tid&3) ^ ((row>>1)&3) (row parity equal
  //     for both since 64 % 8 == 0). Coalesced 64 B per 4 threads. ---
  int srow = tid >> 2;                               // 0..63
  int qq = (tid & 3) ^ ((tid >> 3) & 3);
  const char* gA = l2q + ((size_t)(bi * BM + srow)) * DIMS + qq * 16;
  const char* gB = l2q + ((size_t)(bj * BM + srow)) * DIMS + qq * 16;

  // --- fragment read offsets (bytes; verified zero-conflict swizzle) ---
  int fcB = (g ^ ((laneq >> 1) & 3)) * 16;           // swizzled 16B chunk slot
  int aOffB = (wr * 64 + laneq) * 64 + fcB;
  int bOffB = 8192 + (nc * 64 + laneq) * 64 + fcB;

  i32x4 aU[4], bR[4];

  #pragma unroll 1
  for (int kt = 0; kt < NTILES; ++kt) {
    __syncthreads();                              // prev tile's reads done
    // stage tile kt: A rows 0-63, 64-127; B rows 0-63, 64-127
    load_lds16(gA + (size_t)kt * BKB, &ldsbuf[w * 1024]);
    load_lds16(gA + (size_t)64 * DIMS + (size_t)kt * BKB, &ldsbuf[4096 + w * 1024]);
    load_lds16(gB + (size_t)kt * BKB, &ldsbuf[8192 + w * 1024]);
    load_lds16(gB + (size_t)64 * DIMS + (size_t)kt * BKB, &ldsbuf[12288 + w * 1024]);
    __syncthreads();                              // drains vmcnt -> visible

    #pragma unroll
    for (int n = 0; n < 4; n++)
      bR[n] = *(const i32x4*)&ldsbuf[bOffB + n * 1024];
    #pragma unroll
    for (int m = 0; m < 4; m++)
      aU[m] = *(const i32x4*)&ldsbuf[aOffB + m * 1024];
    #pragma unroll
    for (int m = 0; m < 4; m++)
      #pragma unroll
      for (int n = 0; n < 4; n++)
        acc[m][n] = __builtin_amdgcn_mfma_i32_16x16x64_i8(aU[m], bR[n],
                                                          acc[m][n], 0, 0, 0);
  }

  // ---- fused masked reduction (r1 geometry + r9 scaling, both verified) ----
  // acc[m][n][r] = Gq[bi*128 + wr*64 + m*16 + g*4 + r]
  //                  [bj*128 + nc*64 + n*16 + laneq]
  int tcol[4];
  float tcr[4];
  #pragma unroll
  for (int n = 0; n < 4; n++) {
    int idx = bj * BM + nc * 64 + n * 16 + laneq;
    tcol[n] = tgt[idx];
    tcr[n] = recip[idx];
  }
  int rbase = bi * BM + wr * 64 + g * 4;

  #pragma unroll
  for (int m = 0; m < 4; m++) {
    #pragma unroll
    for (int r = 0; r < 4; r++) {
      int grow = rbase + m * 16 + r;
      int trow = tgt[grow];
      float rrw = recip[grow];
      float ap = -__builtin_inff(), an = __builtin_inff();
      #pragma unroll
      for (int n = 0; n < 4; n++) {
        float d = -(float)acc[m][n][r] * rrw * tcr[n];
        bool same = (trow == tcol[n]);
        ap = same ? fmaxf(ap, d) : ap;
        an = same ? an : fminf(an, d);
      }
      #pragma unroll
      for (int s = 1; s < 16; s <<= 1) {
        ap = fmaxf(ap, __shfl_xor(ap, s));
        an = fminf(an, __shfl_xor(an, s));
      }
      if (laneq == 0) {
        atomicMaxF(&dap[grow], ap);
        atomicMinF(&dan[grow], an);
      }
    }
  }
}

// ---------------- final loss ----------------
__global__ __launch_bounds__(256) void loss_kernel(const float* __restrict__ dap,
                                                   const float* __restrict__ dan,
                                                   float* __restrict__ out) {
  int t = threadIdx.x;
  float s = 0.f;
  for (int i = t; i < NROWS; i += 256) {
    float v = dap[i] - dan[i] + MARGIN_F;
    s += v > 0.f ? v : 0.f;
  }
  #pragma unroll
  for (int sh = 1; sh < 64; sh <<= 1) s += __shfl_xor(s, sh);
  __shared__ float ws[4];
  if ((t & 63) == 0) ws[t >> 6] = s;
  __syncthreads();
  if (t == 0) out[0] = (ws[0] + ws[1] + ws[2] + ws[3]) * (1.0f / (float)NROWS);
}

extern "C" void kernel_launch(void* const* d_in, const int* in_sizes, int n_in,
                              void* d_out, int out_size, void* d_ws, size_t ws_size,
                              hipStream_t stream) {
  const float* inputs = (const float*)d_in[0];
  const int* targets = (const int*)d_in[1];
  char* l2q = (char*)d_ws;
  float* recip = (float*)((char*)d_ws + (size_t)NROWS * DIMS);
  float* dap = recip + NROWS;
  float* dan = dap + NROWS;
  float* out = (float*)d_out;

  hipLaunchKernelGGL(norm_kernel, dim3(NROWS), dim3(256), 0, stream,
                     inputs, l2q, recip, dap, dan);
  hipLaunchKernelGGL(gemm_reduce_kernel, dim3(NTB * NTB), dim3(256), 0, stream,
                     l2q, targets, recip, dap, dan);
  hipLaunchKernelGGL(loss_kernel, dim3(1), dim3(256), 0, stream, dap, dan, out);
}